// Round 1
// baseline (139.065 us; speedup 1.0000x reference)
//
#include <hip/hip_runtime.h>
#include <hip/hip_bf16.h>

// RestrictedNN DAG. Round 6: full fusion.
//  - ONE tree kernel: block = 16 batch rows, loops all 8 leaf slices.
//    x tile + per-slice weights for s+1 are prefetched into registers during
//    slice s compute; h2 accumulates in LDS (f32); root 128->16->1 runs
//    in-block after the slice loop. k_root and the h2 global round-trip are
//    gone. Arithmetic identical to round 5 (absmax should be unchanged).
// B=4096, L0=512 leaves (G=8,H=16), L1=64, L2=8 (FAN=8), root 128->16.

#define TB 16
#define XSS 520      // ushorts per x row (512+8): rows 16B-aligned
#define H0S 1032     // ushorts per h0 row (1024+8)
#define H1S 136      // ushorts per h1 row (128+8)
#define H2S 132      // floats per h2 row (128+4)

typedef __attribute__((ext_vector_type(8))) short short8;
typedef __attribute__((ext_vector_type(4))) float floatx4;

__device__ __forceinline__ float sigf(float v) {
    return __builtin_amdgcn_rcpf(1.0f + __expf(-v));
}
__device__ __forceinline__ float bflo(unsigned int p) {
    return __builtin_bit_cast(float, p << 16);
}
__device__ __forceinline__ float bfhi(unsigned int p) {
    return __builtin_bit_cast(float, p & 0xffff0000u);
}
__device__ __forceinline__ unsigned int f2bf_u32(float f) {   // RNE, bf16 in low 16
    unsigned int u = __builtin_bit_cast(unsigned int, f);
    return (u + 0x7fffu + ((u >> 16) & 1u)) >> 16;
}
__device__ __forceinline__ unsigned short f2bf(float f) {
    return (unsigned short)f2bf_u32(f);
}
__device__ __forceinline__ unsigned int f2bf2(float lo, float hi) {
    return f2bf_u32(lo) | (f2bf_u32(hi) << 16);
}

// ---- prep: transpose W1/W2 per module to bf16 [h][k] fragment layout ----
__global__ __launch_bounds__(256) void k_prep(
    const float* __restrict__ W1, const float* __restrict__ W2,
    unsigned short* __restrict__ W1t, unsigned short* __restrict__ W2t)
{
    __shared__ float wl[128 * 17];
    const int mb = blockIdx.x;              // 0..63 -> W1, 64..71 -> W2
    const float* src = (mb < 64) ? (W1 + (size_t)mb * 2048)
                                 : (W2 + (size_t)(mb - 64) * 2048);
    unsigned short* dst = (mb < 64) ? (W1t + (size_t)mb * 2048)
                                    : (W2t + (size_t)(mb - 64) * 2048);
    const int tid = threadIdx.x;
#pragma unroll
    for (int i = 0; i < 8; ++i) {
        const int idx = tid + i * 256;      // [k][h] in, coalesced
        wl[(idx >> 4) * 17 + (idx & 15)] = src[idx];
    }
    __syncthreads();
#pragma unroll
    for (int i = 0; i < 4; ++i) {
        const int u  = tid + i * 256;       // uint index over [h][k] bf16 out
        const int h  = u >> 6;
        const int k  = (u & 63) * 2;
        ((unsigned int*)dst)[u] = f2bf2(wl[k * 17 + h], wl[(k + 1) * 17 + h]);
    }
}

// ---- fused tree: gene + h0 + h1 + h2 + root, one block per 16 batch rows ----
__global__ __launch_bounds__(512, 2) void k_tree(
    const float* __restrict__ x, const float* __restrict__ Wg,
    const float* __restrict__ bg, const float* __restrict__ W0,
    const unsigned short* __restrict__ W1t, const unsigned short* __restrict__ W2t,
    const float* __restrict__ W3, const float* __restrict__ Wf,
    float* __restrict__ out)
{
    __shared__ __align__(16) unsigned short xs[TB * XSS];    // 16640 B
    __shared__ __align__(16) unsigned short h0s[TB * H0S];   // 33024 B
    __shared__ __align__(16) unsigned short h1u[TB * H1S];   //  4352 B
    __shared__ __align__(16) float h2s[TB * H2S];            //  8448 B
    __shared__ float w3s[2048];                              //  8192 B
    __shared__ float wfs[16];

    const int tid  = threadIdx.x;
    const int b0   = blockIdx.x * TB;
    const int lane = tid & 63;
    const int wv   = tid >> 6;               // 0..7
    const int half = tid >> 8;               // rows 0-7 / 8-15 in phase A
    const int m_l  = (tid >> 2) & 63;        // local leaf module
    const int hq   = tid & 3;                // h quad
    const int n    = lane & 15, q = lane >> 4;

    // stage root weights once
    *(float4*)&w3s[tid * 4] = *(const float4*)(W3 + tid * 4);
    if (tid < 16) wfs[tid] = Wf[tid];

    // ---------- prologue: slice 0 loads ----------
    float4 xp[4];
    {
        const float* xb = x + (size_t)b0 * 4096;
#pragma unroll
        for (int t = 0; t < 4; ++t) {
            const int i = tid + t * 512, r = i >> 7, c4 = i & 127;
            xp[t] = *(const float4*)(xb + (size_t)r * 4096 + c4 * 4);
        }
    }
    float4 w0r[8], wg0, wg1, bg0, bg1;
#pragma unroll
    for (int g = 0; g < 8; ++g)
        w0r[g] = *(const float4*)(W0 + (size_t)m_l * 128 + g * 16 + hq * 4);
    wg0 = *(const float4*)(Wg + m_l * 8);
    wg1 = *(const float4*)(Wg + m_l * 8 + 4);
    bg0 = *(const float4*)(bg + m_l * 8);
    bg1 = *(const float4*)(bg + m_l * 8 + 4);

    short8 w1r[4];
#pragma unroll
    for (int ks = 0; ks < 4; ++ks)
        w1r[ks] = *(const short8*)(W1t + (size_t)wv * 2048 + n * 128 + q * 8 + ks * 32);
    short8 w2r[4];
    if (wv == 0) {
#pragma unroll
        for (int ks = 0; ks < 4; ++ks)
            w2r[ks] = *(const short8*)(W2t + n * 128 + q * 8 + ks * 32);
    }

#pragma unroll
    for (int t = 0; t < 4; ++t) {
        const int i = tid + t * 512, r = i >> 7, c4 = i & 127;
        *(uint2*)&xs[r * XSS + c4 * 4] =
            make_uint2(f2bf2(xp[t].x, xp[t].y), f2bf2(xp[t].z, xp[t].w));
    }
    __syncthreads();

    // ---------- slice loop ----------
#pragma unroll 1
    for (int s = 0; s < 8; ++s) {
        // issue x loads for slice s+1 (land during phase A)
        if (s < 7) {
            const float* xb = x + (size_t)b0 * 4096 + (s + 1) * 512;
#pragma unroll
            for (int t = 0; t < 4; ++t) {
                const int i = tid + t * 512, r = i >> 7, c4 = i & 127;
                xp[t] = *(const float4*)(xb + (size_t)r * 4096 + c4 * 4);
            }
        }

        // ---- phase A: gene + h0 for this slice (8 rows per thread) ----
        {
            unsigned short* h0base = &h0s[m_l * 16 + hq * 4];
#pragma unroll 4
            for (int bb = 0; bb < 8; ++bb) {
                const int b = half * 8 + bb;
                const uint4 xv = *(const uint4*)&xs[b * XSS + m_l * 8];
                float gene[8];
                gene[0] = fmaf(bflo(xv.x), wg0.x, bg0.x);
                gene[1] = fmaf(bfhi(xv.x), wg0.y, bg0.y);
                gene[2] = fmaf(bflo(xv.y), wg0.z, bg0.z);
                gene[3] = fmaf(bfhi(xv.y), wg0.w, bg0.w);
                gene[4] = fmaf(bflo(xv.z), wg1.x, bg1.x);
                gene[5] = fmaf(bfhi(xv.z), wg1.y, bg1.y);
                gene[6] = fmaf(bflo(xv.w), wg1.z, bg1.z);
                gene[7] = fmaf(bfhi(xv.w), wg1.w, bg1.w);
                float a0 = 0.f, a1 = 0.f, a2 = 0.f, a3 = 0.f;
#pragma unroll
                for (int g = 0; g < 8; ++g) {
                    a0 = fmaf(gene[g], w0r[g].x, a0);
                    a1 = fmaf(gene[g], w0r[g].y, a1);
                    a2 = fmaf(gene[g], w0r[g].z, a2);
                    a3 = fmaf(gene[g], w0r[g].w, a3);
                }
                *(uint2*)(h0base + b * H0S) =
                    make_uint2(f2bf2(sigf(a0), sigf(a1)), f2bf2(sigf(a2), sigf(a3)));
            }
        }
        __syncthreads();   // h0s ready; xs free

        // ---- phase B: h1 MFMA, wave wv -> module wv of this slice ----
        {
            const unsigned short* am = &h0s[n * H0S + wv * 128 + q * 8];
            floatx4 acc = {0.f, 0.f, 0.f, 0.f};
#pragma unroll
            for (int ks = 0; ks < 4; ++ks) {
                const short8 av = *(const short8*)(am + ks * 32);
                acc = __builtin_amdgcn_mfma_f32_16x16x32_bf16(av, w1r[ks], acc, 0, 0, 0);
            }
#pragma unroll
            for (int r = 0; r < 4; ++r)
                h1u[(q * 4 + r) * H1S + wv * 16 + n] = f2bf(sigf(acc[r]));
        }
        // overlap: write staged x(s+1) into xs, reload phase-A weights
        if (s < 7) {
#pragma unroll
            for (int t = 0; t < 4; ++t) {
                const int i = tid + t * 512, r = i >> 7, c4 = i & 127;
                *(uint2*)&xs[r * XSS + c4 * 4] =
                    make_uint2(f2bf2(xp[t].x, xp[t].y), f2bf2(xp[t].z, xp[t].w));
            }
            const int m2 = (s + 1) * 64 + m_l;
#pragma unroll
            for (int g = 0; g < 8; ++g)
                w0r[g] = *(const float4*)(W0 + (size_t)m2 * 128 + g * 16 + hq * 4);
            wg0 = *(const float4*)(Wg + m2 * 8);
            wg1 = *(const float4*)(Wg + m2 * 8 + 4);
            bg0 = *(const float4*)(bg + m2 * 8);
            bg1 = *(const float4*)(bg + m2 * 8 + 4);
        }
        __syncthreads();   // h1u ready

        // ---- phase C: h2 MFMA (module s), wave 0 -> h2s LDS column ----
        if (wv == 0) {
            const unsigned short* am = &h1u[n * H1S + q * 8];
            floatx4 acc = {0.f, 0.f, 0.f, 0.f};
#pragma unroll
            for (int ks = 0; ks < 4; ++ks) {
                const short8 av = *(const short8*)(am + ks * 32);
                acc = __builtin_amdgcn_mfma_f32_16x16x32_bf16(av, w2r[ks], acc, 0, 0, 0);
            }
#pragma unroll
            for (int r = 0; r < 4; ++r)
                h2s[(q * 4 + r) * H2S + s * 16 + n] = sigf(acc[r]);
        }
        // overlap: reload MFMA B-fragments for slice s+1
        if (s < 7) {
#pragma unroll
            for (int ks = 0; ks < 4; ++ks)
                w1r[ks] = *(const short8*)(W1t + (size_t)((s + 1) * 8 + wv) * 2048
                                           + n * 128 + q * 8 + ks * 32);
            if (wv == 0) {
#pragma unroll
                for (int ks = 0; ks < 4; ++ks)
                    w2r[ks] = *(const short8*)(W2t + (size_t)(s + 1) * 2048
                                               + n * 128 + q * 8 + ks * 32);
            }
        }
        __syncthreads();   // h1u free for next B; h2s column committed
    }

    // ---------- root: 128->16 sigmoid + dot(16), threads 0..255 ----------
    if (tid < 256) {
        const int b = tid >> 4, h = tid & 15;
        float acc = 0.f;
#pragma unroll
        for (int k4 = 0; k4 < 32; ++k4) {
            const float4 hv = *(const float4*)&h2s[b * H2S + k4 * 4];
            acc = fmaf(hv.x, w3s[(k4 * 4 + 0) * 16 + h], acc);
            acc = fmaf(hv.y, w3s[(k4 * 4 + 1) * 16 + h], acc);
            acc = fmaf(hv.z, w3s[(k4 * 4 + 2) * 16 + h], acc);
            acc = fmaf(hv.w, w3s[(k4 * 4 + 3) * 16 + h], acc);
        }
        float v = sigf(acc) * wfs[h];
        v += __shfl_down(v, 8, 16);
        v += __shfl_down(v, 4, 16);
        v += __shfl_down(v, 2, 16);
        v += __shfl_down(v, 1, 16);
        if (h == 0) out[b0 + b] = v;
    }
}

extern "C" void kernel_launch(void* const* d_in, const int* in_sizes, int n_in,
                              void* d_out, int out_size, void* d_ws, size_t ws_size,
                              hipStream_t stream) {
    const float* x  = (const float*)d_in[0];
    const float* Wg = (const float*)d_in[1];
    const float* bg = (const float*)d_in[2];
    const float* W0 = (const float*)d_in[3];
    const float* W1 = (const float*)d_in[4];
    const float* W2 = (const float*)d_in[5];
    const float* W3 = (const float*)d_in[6];
    const float* Wf = (const float*)d_in[7];
    float* out = (float*)d_out;

    unsigned short* W1t = (unsigned short*)d_ws;              // 256 KB
    unsigned short* W2t = W1t + (size_t)64 * 2048;            //  32 KB

    k_prep<<<dim3(72), dim3(256), 0, stream>>>(W1, W2, W1t, W2t);
    k_tree<<<dim3(4096 / TB), dim3(512), 0, stream>>>(x, Wg, bg, W0, W1t, W2t,
                                                      W3, Wf, out);
}